// Round 4
// baseline (266.632 us; speedup 1.0000x reference)
//
#include <hip/hip_runtime.h>
#include <stdint.h>

// f32 I/O. Two-phase: pre_cast builds bf16 X, bf16 X^T, f32 |x|^2 in d_ws once;
// gauss_main runs both GEMMs with zero staging conversions and ZERO in-loop
// barriers (P bands are wave-private). Fallback to r11 kernel if ws too small.
// R1: 8 waves = 4 bands x 2 S-halves (intensity-preserving occupancy).
// R2: batch-affine XCD swizzle (FETCH 78->20MB, proven by counters; kept).
// R3 lesson: hint-prefetch got sunk by the compiler (VGPR 60->64, no gain);
//     swizzle fixed traffic but time didn't move -> kernel is in-wave
//     latency-bound on the serial chain G1 -> exp -> LDS -> G2.
// R4: T15 double-pipeline. Two pacc banks; body(it) = { load B(it+1); exp(it);
//     G1(it+1) -> other bank; G2(it) }. The G1(it+1) data dependency FORCES the
//     B loads early (can't be sunk), G1's MFMAs overlap exp's VALU, and the
//     LDS P writes drain under G1 before G2 reads them.
#define T_DIM 2048
#define C_DIM 64
#define BT 128
#define BS 128
#define NTILE (T_DIM / BS)
#define PSP 140  // sm_p stride: (4 rows)*(70 dw) % 32 = 24 -> quads hit disjoint banks
#define PS 136   // r11 fallback stride

typedef __bf16 bf16x8v __attribute__((ext_vector_type(8)));
typedef float f32x4 __attribute__((ext_vector_type(4)));

#if defined(__has_builtin)
#if __has_builtin(__builtin_amdgcn_exp2f)
#define EXP2F(x) __builtin_amdgcn_exp2f(x)
#else
#define EXP2F(x) exp2f(x)
#endif
#else
#define EXP2F(x) exp2f(x)
#endif

__device__ __forceinline__ unsigned short f32_to_bf16_rne(float f) {
  union { float f; unsigned int x; } v; v.f = f;
  unsigned int u = v.x;
  u += 0x7fffu + ((u >> 16) & 1u);
  return (unsigned short)(u >> 16);
}
__device__ __forceinline__ uint4 pack8(const unsigned short* v) {
  uint4 u;
  u.x = (unsigned)v[0] | ((unsigned)v[1] << 16);
  u.y = (unsigned)v[2] | ((unsigned)v[3] << 16);
  u.z = (unsigned)v[4] | ((unsigned)v[5] << 16);
  u.w = (unsigned)v[6] | ((unsigned)v[7] << 16);
  return u;
}

// ---------------- pre-pass: f32 -> bf16 X, bf16 X^T, f32 row norms ----------------
__global__ __launch_bounds__(256, 4)
void pre_cast(const float* __restrict__ x, unsigned short* __restrict__ xbf,
              unsigned short* __restrict__ xtbf, float* __restrict__ sq) {
  __shared__ __align__(16) unsigned short tile[64 * 68];
  // batch-affine XCD swizzle (flat%8 == blockIdx.x%8 since gridDim.x=32):
  // XCD c handles batches 4c..4c+3 so gauss_main reads hit the same L2.
  int bx = blockIdx.x, by = blockIdx.y;
  int b, t0i;
  if (gridDim.x == 32 && gridDim.y == 32) {
    const int c = bx & 7;
    const int r = (by << 2) | (bx >> 3);   // 0..127
    b = (c << 2) + (r >> 5);
    t0i = r & 31;
  } else { b = by; t0i = bx; }
  const int t0 = t0i * 64;
  const int tid = threadIdx.x;
  const int r = tid >> 2, q = tid & 3;

  const float* src = x + ((size_t)b * T_DIM + t0 + r) * C_DIM + q * 16;
  float part = 0.f;
  unsigned short vals[16];
#pragma unroll
  for (int i = 0; i < 4; ++i) {
    f32x4 v = *(const f32x4*)(src + 4 * i);
#pragma unroll
    for (int j = 0; j < 4; ++j) { part += v[j] * v[j]; vals[4 * i + j] = f32_to_bf16_rne(v[j]); }
  }
  part += __shfl_xor(part, 1);
  part += __shfl_xor(part, 2);
  if (q == 0) sq[(size_t)b * T_DIM + t0 + r] = part;

  uint4 p0 = pack8(vals), p1 = pack8(vals + 8);
  unsigned short* dst = xbf + ((size_t)b * T_DIM + t0 + r) * C_DIM + q * 16;
  *(uint4*)dst = p0;
  *(uint4*)(dst + 8) = p1;
  *(uint4*)(&tile[r * 68 + q * 16]) = p0;
  *(uint4*)(&tile[r * 68 + q * 16 + 8]) = p1;
  __syncthreads();

  const int cc = tid >> 2, tq = tid & 3;  // 4 consecutive lanes share cc -> 128B coalesced stores
  unsigned short tv[16];
#pragma unroll
  for (int j = 0; j < 16; ++j) tv[j] = tile[(tq * 16 + j) * 68 + cc];
  unsigned short* dT = xtbf + ((size_t)b * C_DIM + cc) * T_DIM + t0 + tq * 16;
  *(uint4*)dT = pack8(tv);
  *(uint4*)(dT + 8) = pack8(tv + 8);
}

// ---------------- main: barrier-free fused kernel, T15 double-pipeline ----------------
// HW-verified 16x16x32 bf16 MFMA layouts (m89/m91/m97/m120):
//   A: A[m=lane&15][k=(lane>>4)*8+j]; B: lane reads row n of B^T, k-contig
//   C/D: col=lane&15, row=(lane>>4)*4+reg

// One pipeline stage: exp+store P(it) from PA, G1(it+1)->PB, G2(it).
#define PIPE_BODY(PA, PB)                                                          \
  {                                                                                \
    const int scur = it * BS + scol;                                               \
    const int snxt = ((it + 1) & (NTILE - 1)) * BS + scol; /* wrap: dead G1 once */\
    float sS[4];                                                                   \
    _Pragma("unroll") for (int nt = 0; nt < 4; ++nt)                               \
        sS[nt] = c1 * sqb[scur + nt * 16 + l15];                                   \
    bf16x8v bn[4][2];                                                              \
    _Pragma("unroll") for (int nt = 0; nt < 4; ++nt) {                             \
      const unsigned short* bp = xb + (size_t)(snxt + nt * 16 + l15) * C_DIM + quad * 8; \
      bn[nt][0] = *(const bf16x8v*)bp;                                             \
      bn[nt][1] = *(const bf16x8v*)(bp + 32);                                      \
    }                                                                              \
    /* exp pass on PA (tile it) -> wave-private P rows in LDS */                   \
    _Pragma("unroll") for (int nt = 0; nt < 4; ++nt) {                             \
      _Pragma("unroll") for (int mt = 0; mt < 2; ++mt) {                           \
        _Pragma("unroll") for (int reg = 0; reg < 4; ++reg) {                      \
          float arg = c2 * PA[mt][nt][reg] - (sTr[mt][reg] + sS[nt]);              \
          arg = (arg < 0.f) ? arg : 0.f;                                           \
          sm_p[(trow + mt * 16 + quad * 4 + reg) * PSP + scol + nt * 16 + l15] =   \
              f32_to_bf16_rne(EXP2F(arg));                                         \
        }                                                                          \
      }                                                                            \
    }                                                                              \
    /* G1 for tile it+1 -> PB (consumes bn: forces loads early; MFMAs overlap exp) */ \
    _Pragma("unroll") for (int mt = 0; mt < 2; ++mt)                               \
      _Pragma("unroll") for (int nt = 0; nt < 4; ++nt)                             \
        _Pragma("unroll") for (int r = 0; r < 4; ++r) PB[mt][nt][r] = 0.f;         \
    _Pragma("unroll") for (int nt = 0; nt < 4; ++nt) {                             \
      _Pragma("unroll") for (int kk = 0; kk < 2; ++kk) {                           \
        PB[0][nt] = __builtin_amdgcn_mfma_f32_16x16x32_bf16(qf[0][kk], bn[nt][kk], PB[0][nt], 0, 0, 0); \
        PB[1][nt] = __builtin_amdgcn_mfma_f32_16x16x32_bf16(qf[1][kk], bn[nt][kk], PB[1][nt], 0, 0, 0); \
      }                                                                            \
    }                                                                              \
    /* G2 for tile it: O += P * Xs (A from sm_p, B from bf16 X^T) */               \
    _Pragma("unroll") for (int kk = 0; kk < 2; ++kk) {                             \
      bf16x8v af[2];                                                               \
      _Pragma("unroll") for (int mt = 0; mt < 2; ++mt)                             \
        af[mt] = *(const bf16x8v*)(sm_p + (trow + mt * 16 + l15) * PSP + scol + kk * 32 + quad * 8); \
      _Pragma("unroll") for (int nt = 0; nt < 4; ++nt) {                           \
        bf16x8v bfr = *(const bf16x8v*)(xtb + (size_t)(nt * 16 + l15) * T_DIM + scur + kk * 32 + quad * 8); \
        oacc[0][nt] = __builtin_amdgcn_mfma_f32_16x16x32_bf16(af[0], bfr, oacc[0][nt], 0, 0, 0); \
        oacc[1][nt] = __builtin_amdgcn_mfma_f32_16x16x32_bf16(af[1], bfr, oacc[1][nt], 0, 0, 0); \
      }                                                                            \
    }                                                                              \
    ++it;                                                                          \
  }

__global__ __launch_bounds__(512, 4)
void gauss_main(const float* __restrict__ x, const unsigned short* __restrict__ xbf,
                const unsigned short* __restrict__ xtbf, const float* __restrict__ sqn,
                const float* __restrict__ rs, float* __restrict__ out) {
  __shared__ __align__(16) unsigned short sm_p[BT * PSP]; // P bf16 [t][s]; wave-private (row band x col half)

  // batch-affine XCD swizzle (flat%8 == blockIdx.x%8 since gridDim.x=16):
  // XCD c handles batches 4c..4c+3 -> per-XCD working set 2MB < 4MB L2.
  int bx = blockIdx.x, by = blockIdx.y;
  int b, t0i;
  if (gridDim.x == 16 && gridDim.y == 32) {
    const int c = bx & 7;
    const int r = (by << 1) | (bx >> 3);   // 0..63
    b = (c << 2) + (r >> 4);
    t0i = r & 15;
  } else { b = by; t0i = bx; }
  const int t0 = t0i * BT;

  const int tid = threadIdx.x;
  const int w = tid >> 6, lane = tid & 63, l15 = lane & 15, quad = lane >> 4;
  const int wq = w & 3, sw = w >> 2;     // band index, S-half index
  const int trow = wq * 32;              // this wave's 32-row band
  const int scol = sw * 64;              // this wave's 64-col S half within each 128 tile

  float sigma = rs[0];
  if (!(sigma == sigma) || !(sigma >= 0.f) || sigma > 1e3f) sigma = 0.01f;
  const float c1 = sigma * 1.4426950408889634f, c2 = 2.0f * c1;

  const unsigned short* xb  = xbf  + (size_t)b * T_DIM * C_DIM;
  const unsigned short* xtb = xtbf + (size_t)b * C_DIM * T_DIM;
  const float* sqb = sqn + (size_t)b * T_DIM;

  // Q A-frags (b128 from bf16 X)
  bf16x8v qf[2][2];
#pragma unroll
  for (int mt = 0; mt < 2; ++mt)
#pragma unroll
    for (int kk = 0; kk < 2; ++kk)
      qf[mt][kk] = *(const bf16x8v*)(xb + (size_t)(t0 + trow + mt * 16 + l15) * C_DIM + kk * 32 + quad * 8);

  float sTr[2][4];
#pragma unroll
  for (int mt = 0; mt < 2; ++mt)
#pragma unroll
    for (int reg = 0; reg < 4; ++reg)
      sTr[mt][reg] = c1 * sqb[t0 + trow + mt * 16 + quad * 4 + reg];

  f32x4 oacc[2][4];
#pragma unroll
  for (int mt = 0; mt < 2; ++mt)
#pragma unroll
    for (int nt = 0; nt < 4; ++nt)
#pragma unroll
      for (int r = 0; r < 4; ++r) oacc[mt][nt][r] = 0.f;

  // pipeline prologue: G1(0) -> pA
  f32x4 pA[2][4], pB[2][4];
#pragma unroll
  for (int mt = 0; mt < 2; ++mt)
#pragma unroll
    for (int nt = 0; nt < 4; ++nt)
#pragma unroll
      for (int r = 0; r < 4; ++r) pA[mt][nt][r] = 0.f;
#pragma unroll
  for (int nt = 0; nt < 4; ++nt) {
    const unsigned short* bp = xb + (size_t)(scol + nt * 16 + l15) * C_DIM + quad * 8;
#pragma unroll
    for (int kk = 0; kk < 2; ++kk) {
      bf16x8v bfr = *(const bf16x8v*)(bp + kk * 32);
      pA[0][nt] = __builtin_amdgcn_mfma_f32_16x16x32_bf16(qf[0][kk], bfr, pA[0][nt], 0, 0, 0);
      pA[1][nt] = __builtin_amdgcn_mfma_f32_16x16x32_bf16(qf[1][kk], bfr, pA[1][nt], 0, 0, 0);
    }
  }

  int it = 0;
#pragma unroll 1
  for (int t2 = 0; t2 < NTILE / 2; ++t2) {
    PIPE_BODY(pA, pB)
    PIPE_BODY(pB, pA)
  }

  // combine the two S-half partial accumulators (waves w and w+4), then epilogue
  __syncthreads();
  float* scr = (float*)sm_p;  // reuse: 4 bands x 64 lanes x 33 floats = 33792 B <= 35840
  if (sw == 1) {
#pragma unroll
    for (int mt = 0; mt < 2; ++mt)
#pragma unroll
      for (int nt = 0; nt < 4; ++nt)
#pragma unroll
        for (int reg = 0; reg < 4; ++reg)
          scr[(wq * 64 + lane) * 33 + (mt * 4 + nt) * 4 + reg] = oacc[mt][nt][reg];
  }
  __syncthreads();
  if (sw == 0) {
#pragma unroll
    for (int mt = 0; mt < 2; ++mt) {
#pragma unroll
      for (int nt = 0; nt < 4; ++nt) {
#pragma unroll
        for (int reg = 0; reg < 4; ++reg) {
          int row = trow + mt * 16 + quad * 4 + reg;
          int col = nt * 16 + l15;
          size_t idx = (size_t)((size_t)b * T_DIM + t0 + row) * C_DIM + col;
          float part = scr[(wq * 64 + lane) * 33 + (mt * 4 + nt) * 4 + reg];
          out[idx] = x[idx] + oacc[mt][nt][reg] + part;
        }
      }
    }
  }
}

// ---------------- fallback: proven r11 kernel (ws too small) ----------------
__global__ __launch_bounds__(256, 2)
void gauss_attn_f32(const float* __restrict__ x, const float* __restrict__ rs,
                    float* __restrict__ out) {
  __shared__ __align__(16) unsigned short sm_xst[C_DIM * PS];
  __shared__ __align__(16) unsigned short sm_p[BT * PS];
  __shared__ float sm_sT[BT];
  __shared__ float sm_sS[BS];
  __shared__ float sm_part[2 * BS];

  const int b = blockIdx.y, t0 = blockIdx.x * BT, tid = threadIdx.x;
  const int w = tid >> 6, lane = tid & 63, l15 = lane & 15, quad = lane >> 4;

  float sigma = rs[0];
  if (!(sigma == sigma) || !(sigma >= 0.f) || sigma > 1e3f) sigma = 0.01f;
  const float c1 = sigma * 1.4426950408889634f, c2 = 2.0f * c1;
  const float* xb = x + (size_t)b * T_DIM * C_DIM;

  if (tid < BT) {
    const f32x4* r4 = (const f32x4*)(xb + (size_t)(t0 + tid) * C_DIM);
    float s = 0.f;
#pragma unroll
    for (int i = 0; i < 16; ++i) { f32x4 v = r4[i]; s += v[0]*v[0] + v[1]*v[1] + v[2]*v[2] + v[3]*v[3]; }
    sm_sT[tid] = s;
  }
  bf16x8v qf[2][2];
#pragma unroll
  for (int mt = 0; mt < 2; ++mt) {
    const float* qp = xb + (size_t)(t0 + w * 32 + mt * 16 + l15) * C_DIM + quad * 8;
#pragma unroll
    for (int kk = 0; kk < 2; ++kk) {
      f32x4 a0 = *(const f32x4*)(qp + kk * 32);
      f32x4 a1 = *(const f32x4*)(qp + kk * 32 + 4);
      union { unsigned short u[8]; bf16x8v v; } pk;
#pragma unroll
      for (int j = 0; j < 4; ++j) { pk.u[j] = f32_to_bf16_rne(a0[j]); pk.u[4+j] = f32_to_bf16_rne(a1[j]); }
      qf[mt][kk] = pk.v;
    }
  }
  __syncthreads();
  float sTr[2][4];
#pragma unroll
  for (int mt = 0; mt < 2; ++mt)
#pragma unroll
    for (int reg = 0; reg < 4; ++reg) sTr[mt][reg] = c1 * sm_sT[w * 32 + mt * 16 + quad * 4 + reg];
  f32x4 oacc[2][4];
#pragma unroll
  for (int mt = 0; mt < 2; ++mt)
#pragma unroll
    for (int nt = 0; nt < 4; ++nt)
#pragma unroll
      for (int r = 0; r < 4; ++r) oacc[mt][nt][r] = 0.f;
  const int sidx = tid & 127, h = tid >> 7;
  for (int it = 0; it < T_DIM / BS; ++it) {
    const int s0 = it * BS;
    __syncthreads();
    {
      float part = 0.f;
      const float* sp = xb + (size_t)(s0 + sidx) * C_DIM + h * 32;
#pragma unroll
      for (int r = 0; r < 8; ++r) {
        f32x4 v = *(const f32x4*)(sp + r * 4);
        part += v[0]*v[0] + v[1]*v[1] + v[2]*v[2] + v[3]*v[3];
        const int c0 = h * 32 + r * 4;
        sm_xst[(c0+0)*PS+sidx] = f32_to_bf16_rne(v[0]);
        sm_xst[(c0+1)*PS+sidx] = f32_to_bf16_rne(v[1]);
        sm_xst[(c0+2)*PS+sidx] = f32_to_bf16_rne(v[2]);
        sm_xst[(c0+3)*PS+sidx] = f32_to_bf16_rne(v[3]);
      }
      sm_part[h * BS + sidx] = part;
    }
    __syncthreads();
    if (tid < BS) sm_sS[tid] = sm_part[tid] + sm_part[BS + tid];
    __syncthreads();
    f32x4 pacc[2][8];
#pragma unroll
    for (int mt = 0; mt < 2; ++mt)
#pragma unroll
      for (int nt = 0; nt < 8; ++nt)
#pragma unroll
        for (int r = 0; r < 4; ++r) pacc[mt][nt][r] = 0.f;
#pragma unroll
    for (int nt = 0; nt < 8; ++nt) {
      const float* bp = xb + (size_t)(s0 + nt * 16 + l15) * C_DIM + quad * 8;
#pragma unroll
      for (int kk = 0; kk < 2; ++kk) {
        f32x4 b0 = *(const f32x4*)(bp + kk * 32);
        f32x4 b1 = *(const f32x4*)(bp + kk * 32 + 4);
        union { unsigned short u[8]; bf16x8v v; } pk;
#pragma unroll
        for (int j = 0; j < 4; ++j) { pk.u[j] = f32_to_bf16_rne(b0[j]); pk.u[4+j] = f32_to_bf16_rne(b1[j]); }
        pacc[0][nt] = __builtin_amdgcn_mfma_f32_16x16x32_bf16(qf[0][kk], pk.v, pacc[0][nt], 0, 0, 0);
        pacc[1][nt] = __builtin_amdgcn_mfma_f32_16x16x32_bf16(qf[1][kk], pk.v, pacc[1][nt], 0, 0, 0);
      }
    }
#pragma unroll
    for (int nt = 0; nt < 8; ++nt) {
      const float sSv = c1 * sm_sS[nt * 16 + l15];
#pragma unroll
      for (int mt = 0; mt < 2; ++mt)
#pragma unroll
        for (int reg = 0; reg < 4; ++reg) {
          float arg = c2 * pacc[mt][nt][reg] - (sTr[mt][reg] + sSv);
          arg = (arg < 0.f) ? arg : 0.f;
          sm_p[(w*32+mt*16+quad*4+reg)*PS + nt*16+l15] = f32_to_bf16_rne(EXP2F(arg));
        }
    }
    __syncthreads();
#pragma unroll
    for (int kk = 0; kk < 4; ++kk) {
      bf16x8v af[2];
#pragma unroll
      for (int mt = 0; mt < 2; ++mt)
        af[mt] = *(const bf16x8v*)(sm_p + (w*32+mt*16+l15)*PS + kk*32 + quad*8);
#pragma unroll
      for (int nt = 0; nt < 4; ++nt) {
        bf16x8v bfr = *(const bf16x8v*)(sm_xst + (nt*16+l15)*PS + kk*32 + quad*8);
        oacc[0][nt] = __builtin_amdgcn_mfma_f32_16x16x32_bf16(af[0], bfr, oacc[0][nt], 0, 0, 0);
        oacc[1][nt] = __builtin_amdgcn_mfma_f32_16x16x32_bf16(af[1], bfr, oacc[1][nt], 0, 0, 0);
      }
    }
  }
#pragma unroll
  for (int mt = 0; mt < 2; ++mt)
#pragma unroll
    for (int nt = 0; nt < 4; ++nt)
#pragma unroll
      for (int reg = 0; reg < 4; ++reg) {
        int row = w * 32 + mt * 16 + quad * 4 + reg;
        int col = nt * 16 + l15;
        size_t idx = (size_t)((size_t)b * T_DIM + t0 + row) * C_DIM + col;
        out[idx] = x[idx] + oacc[mt][nt][reg];
      }
}

extern "C" void kernel_launch(void* const* d_in, const int* in_sizes, int n_in,
                              void* d_out, int out_size, void* d_ws, size_t ws_size,
                              hipStream_t stream) {
  const float* x  = (const float*)d_in[0];
  const float* rs = (const float*)d_in[1];
  float* outp = (float*)d_out;
  int B = in_sizes[0] / (T_DIM * C_DIM);
  if (B < 1) B = 1;
  size_t xel = (size_t)B * T_DIM * C_DIM;
  size_t need = xel * 2 * 2 + (size_t)B * T_DIM * 4;
  if (ws_size >= need) {
    unsigned short* xbf  = (unsigned short*)d_ws;
    unsigned short* xtbf = xbf + xel;
    float* sq = (float*)(xtbf + xel);
    pre_cast<<<dim3(T_DIM / 64, B), 256, 0, stream>>>(x, xbf, xtbf, sq);
    gauss_main<<<dim3(T_DIM / BT, B), 512, 0, stream>>>(x, xbf, xtbf, sq, rs, outp);
  } else {
    gauss_attn_f32<<<dim3(T_DIM / BT, B), 256, 0, stream>>>(x, rs, outp);
  }
}

// Round 5
// 182.138 us; speedup vs baseline: 1.4639x; 1.4639x over previous
//
#include <hip/hip_runtime.h>
#include <stdint.h>

// f32 I/O. Two-phase: pre_cast builds bf16 X, bf16 X^T, f32 |x|^2 in d_ws once;
// gauss_main: staged 2-phase fused kernel. Fallback to r11 kernel if ws too small.
// R1: 8 waves = 4 bands x 2 S-halves (intensity-preserving occupancy).
// R2: batch-affine XCD swizzle (FETCH 78->20MB proven; kept).
// R3 lesson: L2-hit vs L3 latency made no difference -> not miss-latency-bound.
// R4 lesson: T15 double-bank pacc spilled at the 128-VGPR/4-wave cap
//     (WRITE_SIZE 16->191MB scratch). Reverted.
// R5: the B-frag globals were 16-row strided gathers (16 cache lines per b128,
//     2.3x fetch amplification, ~16 segmented vmem insts/iter/wave on the
//     critical path). Classic fix: cooperatively stage xs[128] and xst[64]
//     tiles in LDS with COALESCED loads (4x b128/thread), 2 barriers/iter,
//     fragments via ds_read_b128 (aligned, bank-uniform strides 72/136).
//     Next-tile loads issue after barrier-1, pinned before barrier-2 (T14).
#define T_DIM 2048
#define C_DIM 64
#define BT 128
#define BS 128
#define NTILE (T_DIM / BS)
#define PSP 140  // sm_p stride: proven 0-conflict layout
#define XSS 72   // xs row stride (els): 144B, 16B-aligned rows, uniform banks
#define XTS 136  // xst row stride (els): 272B, 16B-aligned rows, uniform banks
#define PS 136   // r11 fallback stride

typedef __bf16 bf16x8v __attribute__((ext_vector_type(8)));
typedef float f32x4 __attribute__((ext_vector_type(4)));

#if defined(__has_builtin)
#if __has_builtin(__builtin_amdgcn_exp2f)
#define EXP2F(x) __builtin_amdgcn_exp2f(x)
#else
#define EXP2F(x) exp2f(x)
#endif
#else
#define EXP2F(x) exp2f(x)
#endif

__device__ __forceinline__ unsigned short f32_to_bf16_rne(float f) {
  union { float f; unsigned int x; } v; v.f = f;
  unsigned int u = v.x;
  u += 0x7fffu + ((u >> 16) & 1u);
  return (unsigned short)(u >> 16);
}
__device__ __forceinline__ uint4 pack8(const unsigned short* v) {
  uint4 u;
  u.x = (unsigned)v[0] | ((unsigned)v[1] << 16);
  u.y = (unsigned)v[2] | ((unsigned)v[3] << 16);
  u.z = (unsigned)v[4] | ((unsigned)v[5] << 16);
  u.w = (unsigned)v[6] | ((unsigned)v[7] << 16);
  return u;
}

// ---------------- pre-pass: f32 -> bf16 X, bf16 X^T, f32 row norms ----------------
__global__ __launch_bounds__(256, 4)
void pre_cast(const float* __restrict__ x, unsigned short* __restrict__ xbf,
              unsigned short* __restrict__ xtbf, float* __restrict__ sq) {
  __shared__ __align__(16) unsigned short tile[64 * 68];
  int bx = blockIdx.x, by = blockIdx.y;
  int b, t0i;
  if (gridDim.x == 32 && gridDim.y == 32) {
    const int c = bx & 7;
    const int r = (by << 2) | (bx >> 3);   // 0..127
    b = (c << 2) + (r >> 5);
    t0i = r & 31;
  } else { b = by; t0i = bx; }
  const int t0 = t0i * 64;
  const int tid = threadIdx.x;
  const int r = tid >> 2, q = tid & 3;

  const float* src = x + ((size_t)b * T_DIM + t0 + r) * C_DIM + q * 16;
  float part = 0.f;
  unsigned short vals[16];
#pragma unroll
  for (int i = 0; i < 4; ++i) {
    f32x4 v = *(const f32x4*)(src + 4 * i);
#pragma unroll
    for (int j = 0; j < 4; ++j) { part += v[j] * v[j]; vals[4 * i + j] = f32_to_bf16_rne(v[j]); }
  }
  part += __shfl_xor(part, 1);
  part += __shfl_xor(part, 2);
  if (q == 0) sq[(size_t)b * T_DIM + t0 + r] = part;

  uint4 p0 = pack8(vals), p1 = pack8(vals + 8);
  unsigned short* dst = xbf + ((size_t)b * T_DIM + t0 + r) * C_DIM + q * 16;
  *(uint4*)dst = p0;
  *(uint4*)(dst + 8) = p1;
  *(uint4*)(&tile[r * 68 + q * 16]) = p0;
  *(uint4*)(&tile[r * 68 + q * 16 + 8]) = p1;
  __syncthreads();

  const int cc = tid >> 2, tq = tid & 3;  // 4 consecutive lanes share cc -> 128B coalesced stores
  unsigned short tv[16];
#pragma unroll
  for (int j = 0; j < 16; ++j) tv[j] = tile[(tq * 16 + j) * 68 + cc];
  unsigned short* dT = xtbf + ((size_t)b * C_DIM + cc) * T_DIM + t0 + tq * 16;
  *(uint4*)dT = pack8(tv);
  *(uint4*)(dT + 8) = pack8(tv + 8);
}

// ---------------- main: staged 2-phase fused kernel ----------------
// HW-verified 16x16x32 bf16 MFMA layouts (m89/m91/m97/m120):
//   A: A[m=lane&15][k=(lane>>4)*8+j]; B: lane reads row n of B^T, k-contig
//   C/D: col=lane&15, row=(lane>>4)*4+reg

// One iteration: write staged regs CUR -> LDS, barrier, issue loads(it+1)->NXT,
// compute tile it from LDS, pin NXT, barrier.
#define ITER(CUR, NXT)                                                             \
  {                                                                                \
    const int s0 = it * BS;                                                        \
    /* stage tile it into LDS (coalesced pattern established at load time) */     \
    *(uint4*)&sm_xs[xr * XSS + xc]      = a0##CUR;                                 \
    *(uint4*)&sm_xs[xr * XSS + xc + 8]  = a1##CUR;                                 \
    *(uint4*)&sm_xst[tr * XTS + tc]     = b0##CUR;                                 \
    *(uint4*)&sm_xst[tr * XTS + tc + 8] = b1##CUR;                                 \
    __syncthreads();                                                               \
    /* issue next-tile loads; drained at the closing barrier (T14) */              \
    const int sn = ((it + 1) & (NTILE - 1)) * BS;                                  \
    a0##NXT = *(const uint4*)(xb + (size_t)(sn + xr) * C_DIM + xc);                \
    a1##NXT = *(const uint4*)(xb + (size_t)(sn + xr) * C_DIM + xc + 8);            \
    b0##NXT = *(const uint4*)(xtb + (size_t)tr * T_DIM + sn + tc);                 \
    b1##NXT = *(const uint4*)(xtb + (size_t)tr * T_DIM + sn + tc + 8);             \
    /* GEMM1: inner = Q * Xs^T over this wave's 64 s-columns, B-frags from LDS */  \
    float sS[4];                                                                   \
    _Pragma("unroll") for (int nt = 0; nt < 4; ++nt)                               \
        sS[nt] = c1 * sqb[s0 + scol + nt * 16 + l15];                              \
    f32x4 pacc[2][4];                                                              \
    _Pragma("unroll") for (int mt = 0; mt < 2; ++mt)                               \
      _Pragma("unroll") for (int nt = 0; nt < 4; ++nt)                             \
        _Pragma("unroll") for (int r = 0; r < 4; ++r) pacc[mt][nt][r] = 0.f;       \
    _Pragma("unroll") for (int nt = 0; nt < 4; ++nt) {                             \
      const unsigned short* bp = sm_xs + (scol + nt * 16 + l15) * XSS + quad * 8;  \
      _Pragma("unroll") for (int kk = 0; kk < 2; ++kk) {                           \
        bf16x8v bfr = *(const bf16x8v*)(bp + kk * 32);                             \
        pacc[0][nt] = __builtin_amdgcn_mfma_f32_16x16x32_bf16(qf[0][kk], bfr, pacc[0][nt], 0, 0, 0); \
        pacc[1][nt] = __builtin_amdgcn_mfma_f32_16x16x32_bf16(qf[1][kk], bfr, pacc[1][nt], 0, 0, 0); \
      }                                                                            \
    }                                                                              \
    /* exp pass -> wave-private P rows in sm_p */                                  \
    _Pragma("unroll") for (int nt = 0; nt < 4; ++nt) {                             \
      _Pragma("unroll") for (int mt = 0; mt < 2; ++mt) {                           \
        _Pragma("unroll") for (int reg = 0; reg < 4; ++reg) {                      \
          float arg = c2 * pacc[mt][nt][reg] - (sTr[mt][reg] + sS[nt]);            \
          arg = (arg < 0.f) ? arg : 0.f;                                           \
          sm_p[(trow + mt * 16 + quad * 4 + reg) * PSP + scol + nt * 16 + l15] =   \
              f32_to_bf16_rne(EXP2F(arg));                                         \
        }                                                                          \
      }                                                                            \
    }                                                                              \
    /* GEMM2: O += P * Xs; A from sm_p, B from xst LDS */                          \
    _Pragma("unroll") for (int kk = 0; kk < 2; ++kk) {                             \
      bf16x8v af[2];                                                               \
      _Pragma("unroll") for (int mt = 0; mt < 2; ++mt)                             \
        af[mt] = *(const bf16x8v*)(sm_p + (trow + mt * 16 + l15) * PSP + scol + kk * 32 + quad * 8); \
      _Pragma("unroll") for (int nt = 0; nt < 4; ++nt) {                           \
        bf16x8v bfr = *(const bf16x8v*)(sm_xst + (nt * 16 + l15) * XTS + scol + kk * 32 + quad * 8); \
        oacc[0][nt] = __builtin_amdgcn_mfma_f32_16x16x32_bf16(af[0], bfr, oacc[0][nt], 0, 0, 0); \
        oacc[1][nt] = __builtin_amdgcn_mfma_f32_16x16x32_bf16(af[1], bfr, oacc[1][nt], 0, 0, 0); \
      }                                                                            \
    }                                                                              \
    /* pin next-tile loads live here (forces issue before this point) */           \
    asm volatile("" :: "v"(a0##NXT.x), "v"(a1##NXT.x), "v"(b0##NXT.x), "v"(b1##NXT.x)); \
    __syncthreads();                                                               \
    ++it;                                                                          \
  }

__global__ __launch_bounds__(512, 4)
void gauss_main(const float* __restrict__ x, const unsigned short* __restrict__ xbf,
                const unsigned short* __restrict__ xtbf, const float* __restrict__ sqn,
                const float* __restrict__ rs, float* __restrict__ out) {
  __shared__ __align__(16) unsigned short sm_xs[BS * XSS];    // Xs tile  [s][c]
  __shared__ __align__(16) unsigned short sm_xst[C_DIM * XTS];// Xs^T tile [c][s]
  __shared__ __align__(16) unsigned short sm_p[BT * PSP];     // P bf16 [t][s]; wave-private bands

  // batch-affine XCD swizzle: XCD c handles batches 4c..4c+3 (2MB < 4MB L2).
  int bx = blockIdx.x, by = blockIdx.y;
  int b, t0i;
  if (gridDim.x == 16 && gridDim.y == 32) {
    const int c = bx & 7;
    const int r = (by << 1) | (bx >> 3);   // 0..63
    b = (c << 2) + (r >> 4);
    t0i = r & 15;
  } else { b = by; t0i = bx; }
  const int t0 = t0i * BT;

  const int tid = threadIdx.x;
  const int w = tid >> 6, lane = tid & 63, l15 = lane & 15, quad = lane >> 4;
  const int wq = w & 3, sw = w >> 2;     // band index, S-half index
  const int trow = wq * 32;              // this wave's 32-row band
  const int scol = sw * 64;              // this wave's 64-col S half within each 128 tile

  // staging indices: coalesced 32B/thread from xb rows and xtb rows
  const int xr = tid >> 2, xc = (tid & 3) * 16;  // xs:  row 0..127, col {0,16,32,48}
  const int tr = tid >> 3, tc = (tid & 7) * 16;  // xst: row 0..63,  col {0..112}

  float sigma = rs[0];
  if (!(sigma == sigma) || !(sigma >= 0.f) || sigma > 1e3f) sigma = 0.01f;
  const float c1 = sigma * 1.4426950408889634f, c2 = 2.0f * c1;

  const unsigned short* xb  = xbf  + (size_t)b * T_DIM * C_DIM;
  const unsigned short* xtb = xtbf + (size_t)b * C_DIM * T_DIM;
  const float* sqb = sqn + (size_t)b * T_DIM;

  // Q A-frags (b128 from bf16 X; one-time strided read, off the hot loop)
  bf16x8v qf[2][2];
#pragma unroll
  for (int mt = 0; mt < 2; ++mt)
#pragma unroll
    for (int kk = 0; kk < 2; ++kk)
      qf[mt][kk] = *(const bf16x8v*)(xb + (size_t)(t0 + trow + mt * 16 + l15) * C_DIM + kk * 32 + quad * 8);

  float sTr[2][4];
#pragma unroll
  for (int mt = 0; mt < 2; ++mt)
#pragma unroll
    for (int reg = 0; reg < 4; ++reg)
      sTr[mt][reg] = c1 * sqb[t0 + trow + mt * 16 + quad * 4 + reg];

  f32x4 oacc[2][4];
#pragma unroll
  for (int mt = 0; mt < 2; ++mt)
#pragma unroll
    for (int nt = 0; nt < 4; ++nt)
#pragma unroll
      for (int r = 0; r < 4; ++r) oacc[mt][nt][r] = 0.f;

  // prologue: load tile 0 into bank A
  uint4 a0A, a1A, b0A, b1A, a0B, a1B, b0B, b1B;
  a0A = *(const uint4*)(xb + (size_t)xr * C_DIM + xc);
  a1A = *(const uint4*)(xb + (size_t)xr * C_DIM + xc + 8);
  b0A = *(const uint4*)(xtb + (size_t)tr * T_DIM + tc);
  b1A = *(const uint4*)(xtb + (size_t)tr * T_DIM + tc + 8);

  int it = 0;
#pragma unroll 1
  for (int t2 = 0; t2 < NTILE / 2; ++t2) {
    ITER(A, B)
    ITER(B, A)
  }

  // combine the two S-half partial accumulators (waves w and w+4), then epilogue
  __syncthreads();
  float* scr = (float*)sm_p;  // reuse: 4 bands x 64 lanes x 33 floats = 33792 B <= 35840
  if (sw == 1) {
#pragma unroll
    for (int mt = 0; mt < 2; ++mt)
#pragma unroll
      for (int nt = 0; nt < 4; ++nt)
#pragma unroll
        for (int reg = 0; reg < 4; ++reg)
          scr[(wq * 64 + lane) * 33 + (mt * 4 + nt) * 4 + reg] = oacc[mt][nt][reg];
  }
  __syncthreads();
  if (sw == 0) {
#pragma unroll
    for (int mt = 0; mt < 2; ++mt) {
#pragma unroll
      for (int nt = 0; nt < 4; ++nt) {
#pragma unroll
        for (int reg = 0; reg < 4; ++reg) {
          int row = trow + mt * 16 + quad * 4 + reg;
          int col = nt * 16 + l15;
          size_t idx = (size_t)((size_t)b * T_DIM + t0 + row) * C_DIM + col;
          float part = scr[(wq * 64 + lane) * 33 + (mt * 4 + nt) * 4 + reg];
          out[idx] = x[idx] + oacc[mt][nt][reg] + part;
        }
      }
    }
  }
}

// ---------------- fallback: proven r11 kernel (ws too small) ----------------
__global__ __launch_bounds__(256, 2)
void gauss_attn_f32(const float* __restrict__ x, const float* __restrict__ rs,
                    float* __restrict__ out) {
  __shared__ __align__(16) unsigned short sm_xst[C_DIM * PS];
  __shared__ __align__(16) unsigned short sm_p[BT * PS];
  __shared__ float sm_sT[BT];
  __shared__ float sm_sS[BS];
  __shared__ float sm_part[2 * BS];

  const int b = blockIdx.y, t0 = blockIdx.x * BT, tid = threadIdx.x;
  const int w = tid >> 6, lane = tid & 63, l15 = lane & 15, quad = lane >> 4;

  float sigma = rs[0];
  if (!(sigma == sigma) || !(sigma >= 0.f) || sigma > 1e3f) sigma = 0.01f;
  const float c1 = sigma * 1.4426950408889634f, c2 = 2.0f * c1;
  const float* xb = x + (size_t)b * T_DIM * C_DIM;

  if (tid < BT) {
    const f32x4* r4 = (const f32x4*)(xb + (size_t)(t0 + tid) * C_DIM);
    float s = 0.f;
#pragma unroll
    for (int i = 0; i < 16; ++i) { f32x4 v = r4[i]; s += v[0]*v[0] + v[1]*v[1] + v[2]*v[2] + v[3]*v[3]; }
    sm_sT[tid] = s;
  }
  bf16x8v qf[2][2];
#pragma unroll
  for (int mt = 0; mt < 2; ++mt) {
    const float* qp = xb + (size_t)(t0 + w * 32 + mt * 16 + l15) * C_DIM + quad * 8;
#pragma unroll
    for (int kk = 0; kk < 2; ++kk) {
      f32x4 a0 = *(const f32x4*)(qp + kk * 32);
      f32x4 a1 = *(const f32x4*)(qp + kk * 32 + 4);
      union { unsigned short u[8]; bf16x8v v; } pk;
#pragma unroll
      for (int j = 0; j < 4; ++j) { pk.u[j] = f32_to_bf16_rne(a0[j]); pk.u[4+j] = f32_to_bf16_rne(a1[j]); }
      qf[mt][kk] = pk.v;
    }
  }
  __syncthreads();
  float sTr[2][4];
#pragma unroll
  for (int mt = 0; mt < 2; ++mt)
#pragma unroll
    for (int reg = 0; reg < 4; ++reg) sTr[mt][reg] = c1 * sm_sT[w * 32 + mt * 16 + quad * 4 + reg];
  f32x4 oacc[2][4];
#pragma unroll
  for (int mt = 0; mt < 2; ++mt)
#pragma unroll
    for (int nt = 0; nt < 4; ++nt)
#pragma unroll
      for (int r = 0; r < 4; ++r) oacc[mt][nt][r] = 0.f;
  const int sidx = tid & 127, h = tid >> 7;
  for (int it = 0; it < T_DIM / BS; ++it) {
    const int s0 = it * BS;
    __syncthreads();
    {
      float part = 0.f;
      const float* sp = xb + (size_t)(s0 + sidx) * C_DIM + h * 32;
#pragma unroll
      for (int r = 0; r < 8; ++r) {
        f32x4 v = *(const f32x4*)(sp + r * 4);
        part += v[0]*v[0] + v[1]*v[1] + v[2]*v[2] + v[3]*v[3];
        const int c0 = h * 32 + r * 4;
        sm_xst[(c0+0)*PS+sidx] = f32_to_bf16_rne(v[0]);
        sm_xst[(c0+1)*PS+sidx] = f32_to_bf16_rne(v[1]);
        sm_xst[(c0+2)*PS+sidx] = f32_to_bf16_rne(v[2]);
        sm_xst[(c0+3)*PS+sidx] = f32_to_bf16_rne(v[3]);
      }
      sm_part[h * BS + sidx] = part;
    }
    __syncthreads();
    if (tid < BS) sm_sS[tid] = sm_part[tid] + sm_part[BS + tid];
    __syncthreads();
    f32x4 pacc[2][8];
#pragma unroll
    for (int mt = 0; mt < 2; ++mt)
#pragma unroll
      for (int nt = 0; nt < 8; ++nt)
#pragma unroll
        for (int r = 0; r < 4; ++r) pacc[mt][nt][r] = 0.f;
#pragma unroll
    for (int nt = 0; nt < 8; ++nt) {
      const float* bp = xb + (size_t)(s0 + nt * 16 + l15) * C_DIM + quad * 8;
#pragma unroll
      for (int kk = 0; kk < 2; ++kk) {
        f32x4 b0 = *(const f32x4*)(bp + kk * 32);
        f32x4 b1 = *(const f32x4*)(bp + kk * 32 + 4);
        union { unsigned short u[8]; bf16x8v v; } pk;
#pragma unroll
        for (int j = 0; j < 4; ++j) { pk.u[j] = f32_to_bf16_rne(b0[j]); pk.u[4+j] = f32_to_bf16_rne(b1[j]); }
        pacc[0][nt] = __builtin_amdgcn_mfma_f32_16x16x32_bf16(qf[0][kk], pk.v, pacc[0][nt], 0, 0, 0);
        pacc[1][nt] = __builtin_amdgcn_mfma_f32_16x16x32_bf16(qf[1][kk], pk.v, pacc[1][nt], 0, 0, 0);
      }
    }
#pragma unroll
    for (int nt = 0; nt < 8; ++nt) {
      const float sSv = c1 * sm_sS[nt * 16 + l15];
#pragma unroll
      for (int mt = 0; mt < 2; ++mt)
#pragma unroll
        for (int reg = 0; reg < 4; ++reg) {
          float arg = c2 * pacc[mt][nt][reg] - (sTr[mt][reg] + sSv);
          arg = (arg < 0.f) ? arg : 0.f;
          sm_p[(w*32+mt*16+quad*4+reg)*PS + nt*16+l15] = f32_to_bf16_rne(EXP2F(arg));
        }
    }
    __syncthreads();
#pragma unroll
    for (int kk = 0; kk < 4; ++kk) {
      bf16x8v af[2];
#pragma unroll
      for (int mt = 0; mt < 2; ++mt)
        af[mt] = *(const bf16x8v*)(sm_p + (w*32+mt*16+l15)*PS + kk*32 + quad*8);
#pragma unroll
      for (int nt = 0; nt < 4; ++nt) {
        bf16x8v bfr = *(const bf16x8v*)(sm_xst + (nt*16+l15)*PS + kk*32 + quad*8);
        oacc[0][nt] = __builtin_amdgcn_mfma_f32_16x16x32_bf16(af[0], bfr, oacc[0][nt], 0, 0, 0);
        oacc[1][nt] = __builtin_amdgcn_mfma_f32_16x16x32_bf16(af[1], bfr, oacc[1][nt], 0, 0, 0);
      }
    }
  }
#pragma unroll
  for (int mt = 0; mt < 2; ++mt)
#pragma unroll
    for (int nt = 0; nt < 4; ++nt)
#pragma unroll
      for (int reg = 0; reg < 4; ++reg) {
        int row = w * 32 + mt * 16 + quad * 4 + reg;
        int col = nt * 16 + l15;
        size_t idx = (size_t)((size_t)b * T_DIM + t0 + row) * C_DIM + col;
        out[idx] = x[idx] + oacc[mt][nt][reg];
      }
}

extern "C" void kernel_launch(void* const* d_in, const int* in_sizes, int n_in,
                              void* d_out, int out_size, void* d_ws, size_t ws_size,
                              hipStream_t stream) {
  const float* x  = (const float*)d_in[0];
  const float* rs = (const float*)d_in[1];
  float* outp = (float*)d_out;
  int B = in_sizes[0] / (T_DIM * C_DIM);
  if (B < 1) B = 1;
  size_t xel = (size_t)B * T_DIM * C_DIM;
  size_t need = xel * 2 * 2 + (size_t)B * T_DIM * 4;
  if (ws_size >= need) {
    unsigned short* xbf  = (unsigned short*)d_ws;
    unsigned short* xtbf = xbf + xel;
    float* sq = (float*)(xtbf + xel);
    pre_cast<<<dim3(T_DIM / 64, B), 256, 0, stream>>>(x, xbf, xtbf, sq);
    gauss_main<<<dim3(T_DIM / BT, B), 512, 0, stream>>>(x, xbf, xtbf, sq, rs, outp);
  } else {
    gauss_attn_f32<<<dim3(T_DIM / BT, B), 256, 0, stream>>>(x, rs, outp);
  }
}

// Round 7
// 127.518 us; speedup vs baseline: 2.0909x; 1.4283x over previous
//
#include <hip/hip_runtime.h>
#include <stdint.h>

// f32 I/O. Two-phase: pre_cast builds bf16 X, bf16 X^T, f32 |x|^2 in d_ws once;
// gauss_main: staged 2-phase fused kernel. Fallback to r11 kernel if ws too small.
// R1: 8 waves = 4 bands x 2 S-halves. R2: batch-affine XCD swizzle (FETCH 78->20MB).
// R5: coalesced LDS staging of xs/xst tiles (FETCH 33MB = ideal; 132->118us).
// R5 lessons: (a) compiler chose VGPR=64 chasing 8 waves/EU while LDS caps at
//     4/EU -> gratuitous spill (WRITE 167MB scratch stores). (b) bank conflicts
//     1e7 from staging + 2x LDS ops in the b16 P-write pass.
// R6: (1) amdgpu_waves_per_eu(4,4) pins the allocator at the LDS-implied
//     occupancy -> 128 VGPR budget, no spill; single-bank staging regs.
//     (2) swapped GEMM1 operands: mfma(xs,q) makes P lane-local along s
//     (4 consecutive s per lane) -> v_cvt_pk_bf16_f32 pairs + b32 P writes
//     (halves P-write LDS ops, replaces 4-op manual RNE).
// R6b: fix asm pin — uint4 can't bind to a "v" constraint; pin scalar dwords.
#define T_DIM 2048
#define C_DIM 64
#define BT 128
#define BS 128
#define NTILE (T_DIM / BS)
#define PSP 140  // sm_p stride (els): even -> b32 pair writes stay dword-aligned
#define XSS 72   // xs row stride (els): 144B rows -> 4-dw bank rotation on reads
#define XTS 136  // xst row stride (els): 272B rows -> 4-dw bank rotation
#define PS 136   // r11 fallback stride

typedef __bf16 bf16x8v __attribute__((ext_vector_type(8)));
typedef float f32x4 __attribute__((ext_vector_type(4)));

#if defined(__has_builtin)
#if __has_builtin(__builtin_amdgcn_exp2f)
#define EXP2F(x) __builtin_amdgcn_exp2f(x)
#else
#define EXP2F(x) exp2f(x)
#endif
#else
#define EXP2F(x) exp2f(x)
#endif

__device__ __forceinline__ unsigned short f32_to_bf16_rne(float f) {
  union { float f; unsigned int x; } v; v.f = f;
  unsigned int u = v.x;
  u += 0x7fffu + ((u >> 16) & 1u);
  return (unsigned short)(u >> 16);
}
__device__ __forceinline__ uint4 pack8(const unsigned short* v) {
  uint4 u;
  u.x = (unsigned)v[0] | ((unsigned)v[1] << 16);
  u.y = (unsigned)v[2] | ((unsigned)v[3] << 16);
  u.z = (unsigned)v[4] | ((unsigned)v[5] << 16);
  u.w = (unsigned)v[6] | ((unsigned)v[7] << 16);
  return u;
}
// packed f32x2 -> bf16x2 (RNE), one instruction
__device__ __forceinline__ unsigned cvt_pk_bf16(float lo, float hi) {
  unsigned r;
  asm("v_cvt_pk_bf16_f32 %0, %1, %2" : "=v"(r) : "v"(lo), "v"(hi));
  return r;
}

// ---------------- pre-pass: f32 -> bf16 X, bf16 X^T, f32 row norms ----------------
__global__ __launch_bounds__(256, 4)
void pre_cast(const float* __restrict__ x, unsigned short* __restrict__ xbf,
              unsigned short* __restrict__ xtbf, float* __restrict__ sq) {
  __shared__ __align__(16) unsigned short tile[64 * 68];
  int bx = blockIdx.x, by = blockIdx.y;
  int b, t0i;
  if (gridDim.x == 32 && gridDim.y == 32) {
    const int c = bx & 7;
    const int r = (by << 2) | (bx >> 3);   // 0..127
    b = (c << 2) + (r >> 5);
    t0i = r & 31;
  } else { b = by; t0i = bx; }
  const int t0 = t0i * 64;
  const int tid = threadIdx.x;
  const int r = tid >> 2, q = tid & 3;

  const float* src = x + ((size_t)b * T_DIM + t0 + r) * C_DIM + q * 16;
  float part = 0.f;
  unsigned short vals[16];
#pragma unroll
  for (int i = 0; i < 4; ++i) {
    f32x4 v = *(const f32x4*)(src + 4 * i);
#pragma unroll
    for (int j = 0; j < 4; ++j) { part += v[j] * v[j]; vals[4 * i + j] = f32_to_bf16_rne(v[j]); }
  }
  part += __shfl_xor(part, 1);
  part += __shfl_xor(part, 2);
  if (q == 0) sq[(size_t)b * T_DIM + t0 + r] = part;

  uint4 p0 = pack8(vals), p1 = pack8(vals + 8);
  unsigned short* dst = xbf + ((size_t)b * T_DIM + t0 + r) * C_DIM + q * 16;
  *(uint4*)dst = p0;
  *(uint4*)(dst + 8) = p1;
  *(uint4*)(&tile[r * 68 + q * 16]) = p0;
  *(uint4*)(&tile[r * 68 + q * 16 + 8]) = p1;
  __syncthreads();

  const int cc = tid >> 2, tq = tid & 3;  // 4 consecutive lanes share cc -> 128B coalesced stores
  unsigned short tv[16];
#pragma unroll
  for (int j = 0; j < 16; ++j) tv[j] = tile[(tq * 16 + j) * 68 + cc];
  unsigned short* dT = xtbf + ((size_t)b * C_DIM + cc) * T_DIM + t0 + tq * 16;
  *(uint4*)dT = pack8(tv);
  *(uint4*)(dT + 8) = pack8(tv + 8);
}

// ---------------- main: staged 2-phase fused kernel ----------------
// HW-verified 16x16x32 bf16 MFMA layouts (m89/m91/m97/m120):
//   A: A[m=lane&15][k=(lane>>4)*8+j]; B: lane reads row n of B^T, k-contig
//   C/D: col=lane&15 (= B's n), row=(lane>>4)*4+reg (= A's m)
__global__ __attribute__((amdgpu_flat_work_group_size(512, 512), amdgpu_waves_per_eu(4, 4)))
void gauss_main(const float* __restrict__ x, const unsigned short* __restrict__ xbf,
                const unsigned short* __restrict__ xtbf, const float* __restrict__ sqn,
                const float* __restrict__ rs, float* __restrict__ out) {
  __shared__ __align__(16) unsigned short sm_xs[BS * XSS];    // Xs tile  [s][c]
  __shared__ __align__(16) unsigned short sm_xst[C_DIM * XTS];// Xs^T tile [c][s]
  __shared__ __align__(16) unsigned short sm_p[BT * PSP];     // P bf16 [t][s]; wave-private bands

  // batch-affine XCD swizzle: XCD c handles batches 4c..4c+3 (2MB < 4MB L2).
  int bx = blockIdx.x, by = blockIdx.y;
  int b, t0i;
  if (gridDim.x == 16 && gridDim.y == 32) {
    const int c = bx & 7;
    const int r = (by << 1) | (bx >> 3);   // 0..63
    b = (c << 2) + (r >> 4);
    t0i = r & 15;
  } else { b = by; t0i = bx; }
  const int t0 = t0i * BT;

  const int tid = threadIdx.x;
  const int w = tid >> 6, lane = tid & 63, l15 = lane & 15, quad = lane >> 4;
  const int wq = w & 3, sw = w >> 2;     // band index, S-half index
  const int trow = wq * 32;              // this wave's 32-row band
  const int scol = sw * 64;              // this wave's 64-col S half within each 128 tile

  // staging indices: coalesced 32B/thread from xb rows and xtb rows
  const int xr = tid >> 2, xc = (tid & 3) * 16;  // xs:  row 0..127, col {0,16,32,48}
  const int tr = tid >> 3, tc = (tid & 7) * 16;  // xst: row 0..63,  col {0..112}

  float sigma = rs[0];
  if (!(sigma == sigma) || !(sigma >= 0.f) || sigma > 1e3f) sigma = 0.01f;
  const float c1 = sigma * 1.4426950408889634f, c2 = 2.0f * c1;

  const unsigned short* xb  = xbf  + (size_t)b * T_DIM * C_DIM;
  const unsigned short* xtb = xtbf + (size_t)b * C_DIM * T_DIM;
  const float* sqb = sqn + (size_t)b * T_DIM;

  // Q B-frags (b128 from bf16 X; one-time strided read, off the hot loop)
  bf16x8v qf[2][2];
#pragma unroll
  for (int mt = 0; mt < 2; ++mt)
#pragma unroll
    for (int kk = 0; kk < 2; ++kk)
      qf[mt][kk] = *(const bf16x8v*)(xb + (size_t)(t0 + trow + mt * 16 + l15) * C_DIM + kk * 32 + quad * 8);

  // per-lane t-norm: t = trow + mt*16 + l15 (swapped-GEMM1 P layout)
  float sTrL[2];
#pragma unroll
  for (int mt = 0; mt < 2; ++mt)
    sTrL[mt] = c1 * sqb[t0 + trow + mt * 16 + l15];

  f32x4 oacc[2][4];
#pragma unroll
  for (int mt = 0; mt < 2; ++mt)
#pragma unroll
    for (int nt = 0; nt < 4; ++nt)
#pragma unroll
      for (int r = 0; r < 4; ++r) oacc[mt][nt][r] = 0.f;

  // prologue: load tile 0 into staging regs (single bank)
  uint4 a0, a1, b0, b1;
  a0 = *(const uint4*)(xb + (size_t)xr * C_DIM + xc);
  a1 = *(const uint4*)(xb + (size_t)xr * C_DIM + xc + 8);
  b0 = *(const uint4*)(xtb + (size_t)tr * T_DIM + tc);
  b1 = *(const uint4*)(xtb + (size_t)tr * T_DIM + tc + 8);

#pragma unroll 1
  for (int it = 0; it < NTILE; ++it) {
    const int s0 = it * BS;
    // stage tile it into LDS
    *(uint4*)&sm_xs[xr * XSS + xc]      = a0;
    *(uint4*)&sm_xs[xr * XSS + xc + 8]  = a1;
    *(uint4*)&sm_xst[tr * XTS + tc]     = b0;
    *(uint4*)&sm_xst[tr * XTS + tc + 8] = b1;
    __syncthreads();

    // issue next-tile loads into the same regs (pinned live before the
    // closing barrier; HBM/L2 latency hides under the compute below)
    const int sn = ((it + 1) & (NTILE - 1)) * BS;
    a0 = *(const uint4*)(xb + (size_t)(sn + xr) * C_DIM + xc);
    a1 = *(const uint4*)(xb + (size_t)(sn + xr) * C_DIM + xc + 8);
    b0 = *(const uint4*)(xtb + (size_t)tr * T_DIM + sn + tc);
    b1 = *(const uint4*)(xtb + (size_t)tr * T_DIM + sn + tc + 8);

    // GEMM1 (swapped): A = Xs-frag (m=s), B = Q-frag (n=t)
    // -> pacc[mt][nt][reg] = inner[t=trow+mt*16+l15][s=scol+nt*16+quad*4+reg]
    f32x4 pacc[2][4];
#pragma unroll
    for (int mt = 0; mt < 2; ++mt)
#pragma unroll
      for (int nt = 0; nt < 4; ++nt)
#pragma unroll
        for (int r = 0; r < 4; ++r) pacc[mt][nt][r] = 0.f;
#pragma unroll
    for (int nt = 0; nt < 4; ++nt) {
      const unsigned short* bp = sm_xs + (scol + nt * 16 + l15) * XSS + quad * 8;
#pragma unroll
      for (int kk = 0; kk < 2; ++kk) {
        bf16x8v xfr = *(const bf16x8v*)(bp + kk * 32);
        pacc[0][nt] = __builtin_amdgcn_mfma_f32_16x16x32_bf16(xfr, qf[0][kk], pacc[0][nt], 0, 0, 0);
        pacc[1][nt] = __builtin_amdgcn_mfma_f32_16x16x32_bf16(xfr, qf[1][kk], pacc[1][nt], 0, 0, 0);
      }
    }

    // exp pass: lane-local s pairs -> cvt_pk -> b32 P writes (wave-private rows)
#pragma unroll
    for (int nt = 0; nt < 4; ++nt) {
      f32x4 sq4 = *(const f32x4*)(sqb + s0 + scol + nt * 16 + quad * 4);
      float cs0 = c1 * sq4[0], cs1 = c1 * sq4[1], cs2 = c1 * sq4[2], cs3 = c1 * sq4[3];
#pragma unroll
      for (int mt = 0; mt < 2; ++mt) {
        unsigned short* prow = sm_p + (trow + mt * 16 + l15) * PSP + scol + nt * 16 + quad * 4;
        float g0 = c2 * pacc[mt][nt][0] - (sTrL[mt] + cs0);
        float g1 = c2 * pacc[mt][nt][1] - (sTrL[mt] + cs1);
        float g2 = c2 * pacc[mt][nt][2] - (sTrL[mt] + cs2);
        float g3 = c2 * pacc[mt][nt][3] - (sTrL[mt] + cs3);
        g0 = (g0 < 0.f) ? g0 : 0.f;
        g1 = (g1 < 0.f) ? g1 : 0.f;
        g2 = (g2 < 0.f) ? g2 : 0.f;
        g3 = (g3 < 0.f) ? g3 : 0.f;
        *(unsigned*)(prow)     = cvt_pk_bf16(EXP2F(g0), EXP2F(g1));
        *(unsigned*)(prow + 2) = cvt_pk_bf16(EXP2F(g2), EXP2F(g3));
      }
    }
    // no __syncthreads: each wave reads back only its own rows x col-half

    // GEMM2: O += P * Xs; A from sm_p, B from xst LDS
#pragma unroll
    for (int kk = 0; kk < 2; ++kk) {
      bf16x8v af[2];
#pragma unroll
      for (int mt = 0; mt < 2; ++mt)
        af[mt] = *(const bf16x8v*)(sm_p + (trow + mt * 16 + l15) * PSP + scol + kk * 32 + quad * 8);
#pragma unroll
      for (int nt = 0; nt < 4; ++nt) {
        bf16x8v bfr = *(const bf16x8v*)(sm_xst + (nt * 16 + l15) * XTS + scol + kk * 32 + quad * 8);
        oacc[0][nt] = __builtin_amdgcn_mfma_f32_16x16x32_bf16(af[0], bfr, oacc[0][nt], 0, 0, 0);
        oacc[1][nt] = __builtin_amdgcn_mfma_f32_16x16x32_bf16(af[1], bfr, oacc[1][nt], 0, 0, 0);
      }
    }

    // pin next-tile loads live here (prevents sinking past the barrier);
    // scalar dword components — uint4 can't bind to a "v" constraint
    asm volatile("" :: "v"(a0.x), "v"(a0.y), "v"(a0.z), "v"(a0.w),
                       "v"(a1.x), "v"(a1.y), "v"(a1.z), "v"(a1.w),
                       "v"(b0.x), "v"(b0.y), "v"(b0.z), "v"(b0.w),
                       "v"(b1.x), "v"(b1.y), "v"(b1.z), "v"(b1.w));
    __syncthreads();
  }

  // combine the two S-half partial accumulators (waves w and w+4), then epilogue
  __syncthreads();
  float* scr = (float*)sm_p;  // reuse: 4 bands x 64 lanes x 33 floats = 33792 B <= 35840
  if (sw == 1) {
#pragma unroll
    for (int mt = 0; mt < 2; ++mt)
#pragma unroll
      for (int nt = 0; nt < 4; ++nt)
#pragma unroll
        for (int reg = 0; reg < 4; ++reg)
          scr[(wq * 64 + lane) * 33 + (mt * 4 + nt) * 4 + reg] = oacc[mt][nt][reg];
  }
  __syncthreads();
  if (sw == 0) {
#pragma unroll
    for (int mt = 0; mt < 2; ++mt) {
#pragma unroll
      for (int nt = 0; nt < 4; ++nt) {
#pragma unroll
        for (int reg = 0; reg < 4; ++reg) {
          int row = trow + mt * 16 + quad * 4 + reg;
          int col = nt * 16 + l15;
          size_t idx = (size_t)((size_t)b * T_DIM + t0 + row) * C_DIM + col;
          float part = scr[(wq * 64 + lane) * 33 + (mt * 4 + nt) * 4 + reg];
          out[idx] = x[idx] + oacc[mt][nt][reg] + part;
        }
      }
    }
  }
}

// ---------------- fallback: proven r11 kernel (ws too small) ----------------
__global__ __launch_bounds__(256, 2)
void gauss_attn_f32(const float* __restrict__ x, const float* __restrict__ rs,
                    float* __restrict__ out) {
  __shared__ __align__(16) unsigned short sm_xst[C_DIM * PS];
  __shared__ __align__(16) unsigned short sm_p[BT * PS];
  __shared__ float sm_sT[BT];
  __shared__ float sm_sS[BS];
  __shared__ float sm_part[2 * BS];

  const int b = blockIdx.y, t0 = blockIdx.x * BT, tid = threadIdx.x;
  const int w = tid >> 6, lane = tid & 63, l15 = lane & 15, quad = lane >> 4;

  float sigma = rs[0];
  if (!(sigma == sigma) || !(sigma >= 0.f) || sigma > 1e3f) sigma = 0.01f;
  const float c1 = sigma * 1.4426950408889634f, c2 = 2.0f * c1;
  const float* xb = x + (size_t)b * T_DIM * C_DIM;

  if (tid < BT) {
    const f32x4* r4 = (const f32x4*)(xb + (size_t)(t0 + tid) * C_DIM);
    float s = 0.f;
#pragma unroll
    for (int i = 0; i < 16; ++i) { f32x4 v = r4[i]; s += v[0]*v[0] + v[1]*v[1] + v[2]*v[2] + v[3]*v[3]; }
    sm_sT[tid] = s;
  }
  bf16x8v qf[2][2];
#pragma unroll
  for (int mt = 0; mt < 2; ++mt) {
    const float* qp = xb + (size_t)(t0 + w * 32 + mt * 16 + l15) * C_DIM + quad * 8;
#pragma unroll
    for (int kk = 0; kk < 2; ++kk) {
      f32x4 a0 = *(const f32x4*)(qp + kk * 32);
      f32x4 a1 = *(const f32x4*)(qp + kk * 32 + 4);
      union { unsigned short u[8]; bf16x8v v; } pk;
#pragma unroll
      for (int j = 0; j < 4; ++j) { pk.u[j] = f32_to_bf16_rne(a0[j]); pk.u[4+j] = f32_to_bf16_rne(a1[j]); }
      qf[mt][kk] = pk.v;
    }
  }
  __syncthreads();
  float sTr[2][4];
#pragma unroll
  for (int mt = 0; mt < 2; ++mt)
#pragma unroll
    for (int reg = 0; reg < 4; ++reg) sTr[mt][reg] = c1 * sm_sT[w * 32 + mt * 16 + quad * 4 + reg];
  f32x4 oacc[2][4];
#pragma unroll
  for (int mt = 0; mt < 2; ++mt)
#pragma unroll
    for (int nt = 0; nt < 4; ++nt)
#pragma unroll
      for (int r = 0; r < 4; ++r) oacc[mt][nt][r] = 0.f;
  const int sidx = tid & 127, h = tid >> 7;
  for (int it = 0; it < T_DIM / BS; ++it) {
    const int s0 = it * BS;
    __syncthreads();
    {
      float part = 0.f;
      const float* sp = xb + (size_t)(s0 + sidx) * C_DIM + h * 32;
#pragma unroll
      for (int r = 0; r < 8; ++r) {
        f32x4 v = *(const f32x4*)(sp + r * 4);
        part += v[0]*v[0] + v[1]*v[1] + v[2]*v[2] + v[3]*v[3];
        const int c0 = h * 32 + r * 4;
        sm_xst[(c0+0)*PS+sidx] = f32_to_bf16_rne(v[0]);
        sm_xst[(c0+1)*PS+sidx] = f32_to_bf16_rne(v[1]);
        sm_xst[(c0+2)*PS+sidx] = f32_to_bf16_rne(v[2]);
        sm_xst[(c0+3)*PS+sidx] = f32_to_bf16_rne(v[3]);
      }
      sm_part[h * BS + sidx] = part;
    }
    __syncthreads();
    if (tid < BS) sm_sS[tid] = sm_part[tid] + sm_part[BS + tid];
    __syncthreads();
    f32x4 pacc[2][8];
#pragma unroll
    for (int mt = 0; mt < 2; ++mt)
#pragma unroll
      for (int nt = 0; nt < 8; ++nt)
#pragma unroll
        for (int r = 0; r < 4; ++r) pacc[mt][nt][r] = 0.f;
#pragma unroll
    for (int nt = 0; nt < 8; ++nt) {
      const float* bp = xb + (size_t)(s0 + nt * 16 + l15) * C_DIM + quad * 8;
#pragma unroll
      for (int kk = 0; kk < 2; ++kk) {
        f32x4 b0 = *(const f32x4*)(bp + kk * 32);
        f32x4 b1 = *(const f32x4*)(bp + kk * 32 + 4);
        union { unsigned short u[8]; bf16x8v v; } pk;
#pragma unroll
        for (int j = 0; j < 4; ++j) { pk.u[j] = f32_to_bf16_rne(b0[j]); pk.u[4+j] = f32_to_bf16_rne(b1[j]); }
        pacc[0][nt] = __builtin_amdgcn_mfma_f32_16x16x32_bf16(qf[0][kk], pk.v, pacc[0][nt], 0, 0, 0);
        pacc[1][nt] = __builtin_amdgcn_mfma_f32_16x16x32_bf16(qf[1][kk], pk.v, pacc[1][nt], 0, 0, 0);
      }
    }
#pragma unroll
    for (int nt = 0; nt < 8; ++nt) {
      const float sSv = c1 * sm_sS[nt * 16 + l15];
#pragma unroll
      for (int mt = 0; mt < 2; ++mt)
#pragma unroll
        for (int reg = 0; reg < 4; ++reg) {
          float arg = c2 * pacc[mt][nt][reg] - (sTr[mt][reg] + sSv);
          arg = (arg < 0.f) ? arg : 0.f;
          sm_p[(w*32+mt*16+quad*4+reg)*PS + nt*16+l15] = f32_to_bf16_rne(EXP2F(arg));
        }
    }
    __syncthreads();
#pragma unroll
    for (int kk = 0; kk < 4; ++kk) {
      bf16x8v af[2];
#pragma unroll
      for (int mt = 0; mt < 2; ++mt)
        af[mt] = *(const bf16x8v*)(sm_p + (w*32+mt*16+l15)*PS + kk*32 + quad*8);
#pragma unroll
      for (int nt = 0; nt < 4; ++nt) {
        bf16x8v bfr = *(const bf16x8v*)(sm_xst + (nt*16+l15)*PS + kk*32 + quad*8);
        oacc[0][nt] = __builtin_amdgcn_mfma_f32_16x16x32_bf16(af[0], bfr, oacc[0][nt], 0, 0, 0);
        oacc[1][nt] = __builtin_amdgcn_mfma_f32_16x16x32_bf16(af[1], bfr, oacc[1][nt], 0, 0, 0);
      }
    }
  }
#pragma unroll
  for (int mt = 0; mt < 2; ++mt)
#pragma unroll
    for (int nt = 0; nt < 4; ++nt)
#pragma unroll
      for (int reg = 0; reg < 4; ++reg) {
        int row = w * 32 + mt * 16 + quad * 4 + reg;
        int col = nt * 16 + l15;
        size_t idx = (size_t)((size_t)b * T_DIM + t0 + row) * C_DIM + col;
        out[idx] = x[idx] + oacc[mt][nt][reg];
      }
}

extern "C" void kernel_launch(void* const* d_in, const int* in_sizes, int n_in,
                              void* d_out, int out_size, void* d_ws, size_t ws_size,
                              hipStream_t stream) {
  const float* x  = (const float*)d_in[0];
  const float* rs = (const float*)d_in[1];
  float* outp = (float*)d_out;
  int B = in_sizes[0] / (T_DIM * C_DIM);
  if (B < 1) B = 1;
  size_t xel = (size_t)B * T_DIM * C_DIM;
  size_t need = xel * 2 * 2 + (size_t)B * T_DIM * 4;
  if (ws_size >= need) {
    unsigned short* xbf  = (unsigned short*)d_ws;
    unsigned short* xtbf = xbf + xel;
    float* sq = (float*)(xtbf + xel);
    pre_cast<<<dim3(T_DIM / 64, B), 256, 0, stream>>>(x, xbf, xtbf, sq);
    gauss_main<<<dim3(T_DIM / BT, B), 512, 0, stream>>>(x, xbf, xtbf, sq, rs, outp);
  } else {
    gauss_attn_f32<<<dim3(T_DIM / BT, B), 256, 0, stream>>>(x, rs, outp);
  }
}

// Round 10
// 125.373 us; speedup vs baseline: 2.1267x; 1.0171x over previous
//
#include <hip/hip_runtime.h>
#include <stdint.h>

// f32 I/O. Two-phase: pre_cast builds bf16 X, bf16 X^T, f32 |x|^2 in d_ws once;
// gauss_main: staged 2-phase fused kernel. Fallback to r11 kernel if ws too small.
// R1: 8 waves = 4 bands x 2 S-halves. R2: batch-affine XCD swizzle.
// R5: coalesced LDS staging. R6/7: waves_per_eu(4,4) (no spill) + swapped GEMM1
//     + cvt_pk b32 P-writes -> 67us PROVEN.
// R8/R8b lesson: full 3-tile XOR swizzle failed correctness twice (~absmax 110)
//     despite per-lane trace verification; cause not found statically.
// R9 BISECT: R7 kernel verbatim + XOR swizzle ONLY on sm_xs / sm_xst (the two
//     tiles with chunk-granular writes, verified by multi-lane trace). sm_p
//     stays in R7's proven PSP=140 unswizzled layout with R7's b32-pair writes
//     and stride-33 epilogue. Isolates which tile's swizzle path is broken.
#define T_DIM 2048
#define C_DIM 64
#define BT 128
#define BS 128
#define NTILE (T_DIM / BS)
#define PSP 140  // sm_p stride (els), proven R7 layout
#define PS 136   // r11 fallback stride

// swizzled element index: row-major power-of-2 stride, 16B-chunk XOR (row&7)
#define XS_IDX(row, chunk) (((row) << 6) + ((((chunk) ^ ((row) & 7)) << 3)))
#define XT_IDX(row, chunk) (((row) << 7) + ((((chunk) ^ ((row) & 7)) << 3)))

typedef __bf16 bf16x8v __attribute__((ext_vector_type(8)));
typedef float f32x4 __attribute__((ext_vector_type(4)));

#if defined(__has_builtin)
#if __has_builtin(__builtin_amdgcn_exp2f)
#define EXP2F(x) __builtin_amdgcn_exp2f(x)
#else
#define EXP2F(x) exp2f(x)
#endif
#else
#define EXP2F(x) exp2f(x)
#endif

__device__ __forceinline__ unsigned short f32_to_bf16_rne(float f) {
  union { float f; unsigned int x; } v; v.f = f;
  unsigned int u = v.x;
  u += 0x7fffu + ((u >> 16) & 1u);
  return (unsigned short)(u >> 16);
}
__device__ __forceinline__ uint4 pack8(const unsigned short* v) {
  uint4 u;
  u.x = (unsigned)v[0] | ((unsigned)v[1] << 16);
  u.y = (unsigned)v[2] | ((unsigned)v[3] << 16);
  u.z = (unsigned)v[4] | ((unsigned)v[5] << 16);
  u.w = (unsigned)v[6] | ((unsigned)v[7] << 16);
  return u;
}
// packed f32x2 -> bf16x2 (RNE), one instruction
__device__ __forceinline__ unsigned cvt_pk_bf16(float lo, float hi) {
  unsigned r;
  asm("v_cvt_pk_bf16_f32 %0, %1, %2" : "=v"(r) : "v"(lo), "v"(hi));
  return r;
}

// ---------------- pre-pass: f32 -> bf16 X, bf16 X^T, f32 row norms ----------------
__global__ __launch_bounds__(256, 4)
void pre_cast(const float* __restrict__ x, unsigned short* __restrict__ xbf,
              unsigned short* __restrict__ xtbf, float* __restrict__ sq) {
  __shared__ __align__(16) unsigned short tile[64 * 68];
  int bx = blockIdx.x, by = blockIdx.y;
  int b, t0i;
  if (gridDim.x == 32 && gridDim.y == 32) {
    const int c = bx & 7;
    const int r = (by << 2) | (bx >> 3);   // 0..127
    b = (c << 2) + (r >> 5);
    t0i = r & 31;
  } else { b = by; t0i = bx; }
  const int t0 = t0i * 64;
  const int tid = threadIdx.x;
  const int r = tid >> 2, q = tid & 3;

  const float* src = x + ((size_t)b * T_DIM + t0 + r) * C_DIM + q * 16;
  float part = 0.f;
  unsigned short vals[16];
#pragma unroll
  for (int i = 0; i < 4; ++i) {
    f32x4 v = *(const f32x4*)(src + 4 * i);
#pragma unroll
    for (int j = 0; j < 4; ++j) { part += v[j] * v[j]; vals[4 * i + j] = f32_to_bf16_rne(v[j]); }
  }
  part += __shfl_xor(part, 1);
  part += __shfl_xor(part, 2);
  if (q == 0) sq[(size_t)b * T_DIM + t0 + r] = part;

  uint4 p0 = pack8(vals), p1 = pack8(vals + 8);
  unsigned short* dst = xbf + ((size_t)b * T_DIM + t0 + r) * C_DIM + q * 16;
  *(uint4*)dst = p0;
  *(uint4*)(dst + 8) = p1;
  *(uint4*)(&tile[r * 68 + q * 16]) = p0;
  *(uint4*)(&tile[r * 68 + q * 16 + 8]) = p1;
  __syncthreads();

  const int cc = tid >> 2, tq = tid & 3;  // 4 consecutive lanes share cc -> 128B coalesced stores
  unsigned short tv[16];
#pragma unroll
  for (int j = 0; j < 16; ++j) tv[j] = tile[(tq * 16 + j) * 68 + cc];
  unsigned short* dT = xtbf + ((size_t)b * C_DIM + cc) * T_DIM + t0 + tq * 16;
  *(uint4*)dT = pack8(tv);
  *(uint4*)(dT + 8) = pack8(tv + 8);
}

// ---------------- main: staged 2-phase fused kernel ----------------
// HW-verified 16x16x32 bf16 MFMA layouts (m89/m91/m97/m120):
//   A: A[m=lane&15][k=(lane>>4)*8+j]; B: lane reads row n of B^T, k-contig
//   C/D: col=lane&15 (= B's n), row=(lane>>4)*4+reg (= A's m)
__global__ __attribute__((amdgpu_flat_work_group_size(512, 512), amdgpu_waves_per_eu(4, 4)))
void gauss_main(const float* __restrict__ x, const unsigned short* __restrict__ xbf,
                const unsigned short* __restrict__ xtbf, const float* __restrict__ sqn,
                const float* __restrict__ rs, float* __restrict__ out) {
  __shared__ __align__(16) unsigned short sm_xs[BS * 64];      // Xs tile  [s][c], swz (16KB)
  __shared__ __align__(16) unsigned short sm_xst[C_DIM * 128]; // Xs^T tile [c][s], swz (16KB)
  __shared__ __align__(16) unsigned short sm_p[BT * PSP];      // P bf16 [t][s], R7 layout (35KB)

  // batch-affine XCD swizzle: XCD c handles batches 4c..4c+3 (2MB < 4MB L2).
  int bx = blockIdx.x, by = blockIdx.y;
  int b, t0i;
  if (gridDim.x == 16 && gridDim.y == 32) {
    const int c = bx & 7;
    const int r = (by << 1) | (bx >> 3);   // 0..63
    b = (c << 2) + (r >> 4);
    t0i = r & 15;
  } else { b = by; t0i = bx; }
  const int t0 = t0i * BT;

  const int tid = threadIdx.x;
  const int w = tid >> 6, lane = tid & 63, l15 = lane & 15, quad = lane >> 4;
  const int wq = w & 3, sw = w >> 2;     // band index, S-half index
  const int trow = wq * 32;              // this wave's 32-row band
  const int scol = sw * 64;              // this wave's 64-col S half within each 128 tile
  const int sch = sw * 8;                // chunk offset of the S half (64 els = 8 chunks)

  // staging indices: coalesced 32B/thread from xb rows and xtb rows (chunk units)
  const int xr = tid >> 2, xch = (tid & 3) * 2;  // xs:  row 0..127, chunks {0,2,4,6}
  const int tr = tid >> 3, tch = (tid & 7) * 2;  // xst: row 0..63,  chunks {0..14}

  float sigma = rs[0];
  if (!(sigma == sigma) || !(sigma >= 0.f) || sigma > 1e3f) sigma = 0.01f;
  const float c1 = sigma * 1.4426950408889634f, c2 = 2.0f * c1;

  const unsigned short* xb  = xbf  + (size_t)b * T_DIM * C_DIM;
  const unsigned short* xtb = xtbf + (size_t)b * C_DIM * T_DIM;
  const float* sqb = sqn + (size_t)b * T_DIM;

  // Q B-frags (b128 from bf16 X; one-time strided read, off the hot loop)
  bf16x8v qf[2][2];
#pragma unroll
  for (int mt = 0; mt < 2; ++mt)
#pragma unroll
    for (int kk = 0; kk < 2; ++kk)
      qf[mt][kk] = *(const bf16x8v*)(xb + (size_t)(t0 + trow + mt * 16 + l15) * C_DIM + kk * 32 + quad * 8);

  // per-lane t-norm: t = trow + mt*16 + l15 (swapped-GEMM1 P layout)
  float sTrL[2];
#pragma unroll
  for (int mt = 0; mt < 2; ++mt)
    sTrL[mt] = c1 * sqb[t0 + trow + mt * 16 + l15];

  f32x4 oacc[2][4];
#pragma unroll
  for (int mt = 0; mt < 2; ++mt)
#pragma unroll
    for (int nt = 0; nt < 4; ++nt)
#pragma unroll
      for (int r = 0; r < 4; ++r) oacc[mt][nt][r] = 0.f;

  // prologue: load tile 0 into staging regs (single bank)
  uint4 a0, a1, b0, b1;
  a0 = *(const uint4*)(xb + (size_t)xr * C_DIM + xch * 8);
  a1 = *(const uint4*)(xb + (size_t)xr * C_DIM + xch * 8 + 8);
  b0 = *(const uint4*)(xtb + (size_t)tr * T_DIM + tch * 8);
  b1 = *(const uint4*)(xtb + (size_t)tr * T_DIM + tch * 8 + 8);

#pragma unroll 1
  for (int it = 0; it < NTILE; ++it) {
    const int s0 = it * BS;
    // stage tile it into LDS (swizzled destinations, chunk-granular)
    *(uint4*)&sm_xs[XS_IDX(xr, xch)]      = a0;
    *(uint4*)&sm_xs[XS_IDX(xr, xch + 1)]  = a1;
    *(uint4*)&sm_xst[XT_IDX(tr, tch)]     = b0;
    *(uint4*)&sm_xst[XT_IDX(tr, tch + 1)] = b1;
    __syncthreads();

    // issue next-tile loads into the same regs (pinned live before the
    // closing barrier; HBM/L2 latency hides under the compute below)
    const int sn = ((it + 1) & (NTILE - 1)) * BS;
    a0 = *(const uint4*)(xb + (size_t)(sn + xr) * C_DIM + xch * 8);
    a1 = *(const uint4*)(xb + (size_t)(sn + xr) * C_DIM + xch * 8 + 8);
    b0 = *(const uint4*)(xtb + (size_t)tr * T_DIM + sn + tch * 8);
    b1 = *(const uint4*)(xtb + (size_t)tr * T_DIM + sn + tch * 8 + 8);

    // GEMM1 (swapped): A = Xs-frag (m=s), B = Q-frag (n=t)
    // -> pacc[mt][nt][reg] = inner[t=trow+mt*16+l15][s=scol+nt*16+quad*4+reg]
    f32x4 pacc[2][4];
#pragma unroll
    for (int mt = 0; mt < 2; ++mt)
#pragma unroll
      for (int nt = 0; nt < 4; ++nt)
#pragma unroll
        for (int r = 0; r < 4; ++r) pacc[mt][nt][r] = 0.f;
#pragma unroll
    for (int nt = 0; nt < 4; ++nt) {
      const int srow = scol + nt * 16 + l15;
#pragma unroll
      for (int kk = 0; kk < 2; ++kk) {
        bf16x8v xfr = *(const bf16x8v*)&sm_xs[XS_IDX(srow, kk * 4 + quad)];
        pacc[0][nt] = __builtin_amdgcn_mfma_f32_16x16x32_bf16(xfr, qf[0][kk], pacc[0][nt], 0, 0, 0);
        pacc[1][nt] = __builtin_amdgcn_mfma_f32_16x16x32_bf16(xfr, qf[1][kk], pacc[1][nt], 0, 0, 0);
      }
    }

    // exp pass: lane-local s pairs -> cvt_pk -> b32 P writes (R7 proven layout)
#pragma unroll
    for (int nt = 0; nt < 4; ++nt) {
      f32x4 sq4 = *(const f32x4*)(sqb + s0 + scol + nt * 16 + quad * 4);
      float cs0 = c1 * sq4[0], cs1 = c1 * sq4[1], cs2 = c1 * sq4[2], cs3 = c1 * sq4[3];
#pragma unroll
      for (int mt = 0; mt < 2; ++mt) {
        unsigned short* prow = sm_p + (trow + mt * 16 + l15) * PSP + scol + nt * 16 + quad * 4;
        float g0 = c2 * pacc[mt][nt][0] - (sTrL[mt] + cs0);
        float g1 = c2 * pacc[mt][nt][1] - (sTrL[mt] + cs1);
        float g2 = c2 * pacc[mt][nt][2] - (sTrL[mt] + cs2);
        float g3 = c2 * pacc[mt][nt][3] - (sTrL[mt] + cs3);
        g0 = (g0 < 0.f) ? g0 : 0.f;
        g1 = (g1 < 0.f) ? g1 : 0.f;
        g2 = (g2 < 0.f) ? g2 : 0.f;
        g3 = (g3 < 0.f) ? g3 : 0.f;
        *(unsigned*)(prow)     = cvt_pk_bf16(EXP2F(g0), EXP2F(g1));
        *(unsigned*)(prow + 2) = cvt_pk_bf16(EXP2F(g2), EXP2F(g3));
      }
    }
    // no __syncthreads: each wave reads back only its own rows x col-half

    // GEMM2: O += P * Xs; A from sm_p (R7 layout), B from xst LDS (swizzled)
#pragma unroll
    for (int kk = 0; kk < 2; ++kk) {
      bf16x8v af[2];
#pragma unroll
      for (int mt = 0; mt < 2; ++mt)
        af[mt] = *(const bf16x8v*)(sm_p + (trow + mt * 16 + l15) * PSP + scol + kk * 32 + quad * 8);
#pragma unroll
      for (int nt = 0; nt < 4; ++nt) {
        bf16x8v bfr = *(const bf16x8v*)&sm_xst[XT_IDX(nt * 16 + l15, sch + kk * 4 + quad)];
        oacc[0][nt] = __builtin_amdgcn_mfma_f32_16x16x32_bf16(af[0], bfr, oacc[0][nt], 0, 0, 0);
        oacc[1][nt] = __builtin_amdgcn_mfma_f32_16x16x32_bf16(af[1], bfr, oacc[1][nt], 0, 0, 0);
      }
    }

    // pin next-tile loads live here (prevents sinking past the barrier)
    asm volatile("" :: "v"(a0.x), "v"(a0.y), "v"(a0.z), "v"(a0.w),
                       "v"(a1.x), "v"(a1.y), "v"(a1.z), "v"(a1.w),
                       "v"(b0.x), "v"(b0.y), "v"(b0.z), "v"(b0.w),
                       "v"(b1.x), "v"(b1.y), "v"(b1.z), "v"(b1.w));
    __syncthreads();
  }

  // combine the two S-half partial accumulators (waves w and w+4), then epilogue
  // (R7 proven: stride 33, 256x33x4 = 33792 B <= 35840 B sm_p)
  __syncthreads();
  float* scr = (float*)sm_p;
  if (sw == 1) {
#pragma unroll
    for (int mt = 0; mt < 2; ++mt)
#pragma unroll
      for (int nt = 0; nt < 4; ++nt)
#pragma unroll
        for (int reg = 0; reg < 4; ++reg)
          scr[(wq * 64 + lane) * 33 + (mt * 4 + nt) * 4 + reg] = oacc[mt][nt][reg];
  }
  __syncthreads();
  if (sw == 0) {
#pragma unroll
    for (int mt = 0; mt < 2; ++mt) {
#pragma unroll
      for (int nt = 0; nt < 4; ++nt) {
#pragma unroll
        for (int reg = 0; reg < 4; ++reg) {
          int row = trow + mt * 16 + quad * 4 + reg;
          int col = nt * 16 + l15;
          size_t idx = (size_t)((size_t)b * T_DIM + t0 + row) * C_DIM + col;
          float part = scr[(wq * 64 + lane) * 33 + (mt * 4 + nt) * 4 + reg];
          out[idx] = x[idx] + oacc[mt][nt][reg] + part;
        }
      }
    }
  }
}

// ---------------- fallback: proven r11 kernel (ws too small) ----------------
__global__ __launch_bounds__(256, 2)
void gauss_attn_f32(const float* __restrict__ x, const float* __restrict__ rs,
                    float* __restrict__ out) {
  __shared__ __align__(16) unsigned short sm_xst[C_DIM * PS];
  __shared__ __align__(16) unsigned short sm_p[BT * PS];
  __shared__ float sm_sT[BT];
  __shared__ float sm_sS[BS];
  __shared__ float sm_part[2 * BS];

  const int b = blockIdx.y, t0 = blockIdx.x * BT, tid = threadIdx.x;
  const int w = tid >> 6, lane = tid & 63, l15 = lane & 15, quad = lane >> 4;

  float sigma = rs[0];
  if (!(sigma == sigma) || !(sigma >= 0.f) || sigma > 1e3f) sigma = 0.01f;
  const float c1 = sigma * 1.4426950408889634f, c2 = 2.0f * c1;
  const float* xb = x + (size_t)b * T_DIM * C_DIM;

  if (tid < BT) {
    const f32x4* r4 = (const f32x4*)(xb + (size_t)(t0 + tid) * C_DIM);
    float s = 0.f;
#pragma unroll
    for (int i = 0; i < 16; ++i) { f32x4 v = r4[i]; s += v[0]*v[0] + v[1]*v[1] + v[2]*v[2] + v[3]*v[3]; }
    sm_sT[tid] = s;
  }
  bf16x8v qf[2][2];
#pragma unroll
  for (int mt = 0; mt < 2; ++mt) {
    const float* qp = xb + (size_t)(t0 + w * 32 + mt * 16 + l15) * C_DIM + quad * 8;
#pragma unroll
    for (int kk = 0; kk < 2; ++kk) {
      f32x4 a0 = *(const f32x4*)(qp + kk * 32);
      f32x4 a1 = *(const f32x4*)(qp + kk * 32 + 4);
      union { unsigned short u[8]; bf16x8v v; } pk;
#pragma unroll
      for (int j = 0; j < 4; ++j) { pk.u[j] = f32_to_bf16_rne(a0[j]); pk.u[4+j] = f32_to_bf16_rne(a1[j]); }
      qf[mt][kk] = pk.v;
    }
  }
  __syncthreads();
  float sTr[2][4];
#pragma unroll
  for (int mt = 0; mt < 2; ++mt)
#pragma unroll
    for (int reg = 0; reg < 4; ++reg) sTr[mt][reg] = c1 * sm_sT[w * 32 + mt * 16 + quad * 4 + reg];
  f32x4 oacc[2][4];
#pragma unroll
  for (int mt = 0; mt < 2; ++mt)
#pragma unroll
    for (int nt = 0; nt < 4; ++nt)
#pragma unroll
      for (int r = 0; r < 4; ++r) oacc[mt][nt][r] = 0.f;
  const int sidx = tid & 127, h = tid >> 7;
  for (int it = 0; it < T_DIM / BS; ++it) {
    const int s0 = it * BS;
    __syncthreads();
    {
      float part = 0.f;
      const float* sp = xb + (size_t)(s0 + sidx) * C_DIM + h * 32;
#pragma unroll
      for (int r = 0; r < 8; ++r) {
        f32x4 v = *(const f32x4*)(sp + r * 4);
        part += v[0]*v[0] + v[1]*v[1] + v[2]*v[2] + v[3]*v[3];
        const int c0 = h * 32 + r * 4;
        sm_xst[(c0+0)*PS+sidx] = f32_to_bf16_rne(v[0]);
        sm_xst[(c0+1)*PS+sidx] = f32_to_bf16_rne(v[1]);
        sm_xst[(c0+2)*PS+sidx] = f32_to_bf16_rne(v[2]);
        sm_xst[(c0+3)*PS+sidx] = f32_to_bf16_rne(v[3]);
      }
      sm_part[h * BS + sidx] = part;
    }
    __syncthreads();
    if (tid < BS) sm_sS[tid] = sm_part[tid] + sm_part[BS + tid];
    __syncthreads();
    f32x4 pacc[2][8];
#pragma unroll
    for (int mt = 0; mt < 2; ++mt)
#pragma unroll
      for (int nt = 0; nt < 8; ++nt)
#pragma unroll
        for (int r = 0; r < 4; ++r) pacc[mt][nt][r] = 0.f;
#pragma unroll
    for (int nt = 0; nt < 8; ++nt) {
      const float* bp = xb + (size_t)(s0 + nt * 16 + l15) * C_DIM + quad * 8;
#pragma unroll
      for (int kk = 0; kk < 2; ++kk) {
        f32x4 b0 = *(const f32x4*)(bp + kk * 32);
        f32x4 b1 = *(const f32x4*)(bp + kk * 32 + 4);
        union { unsigned short u[8]; bf16x8v v; } pk;
#pragma unroll
        for (int j = 0; j < 4; ++j) { pk.u[j] = f32_to_bf16_rne(b0[j]); pk.u[4+j] = f32_to_bf16_rne(b1[j]); }
        pacc[0][nt] = __builtin_amdgcn_mfma_f32_16x16x32_bf16(qf[0][kk], pk.v, pacc[0][nt], 0, 0, 0);
        pacc[1][nt] = __builtin_amdgcn_mfma_f32_16x16x32_bf16(qf[1][kk], pk.v, pacc[1][nt], 0, 0, 0);
      }
    }
#pragma unroll
    for (int nt = 0; nt < 8; ++nt) {
      const float sSv = c1 * sm_sS[nt * 16 + l15];
#pragma unroll
      for (int mt = 0; mt < 2; ++mt)
#pragma unroll
        for (int reg = 0; reg < 4; ++reg) {
          float arg = c2 * pacc[mt][nt][reg] - (sTr[mt][reg] + sSv);
          arg = (arg < 0.f) ? arg : 0.f;
          sm_p[(w*32+mt*16+quad*4+reg)*PS + nt*16+l15] = f32_to_bf16_rne(EXP2F(arg));
        }
    }
    __syncthreads();
#pragma unroll
    for (int kk = 0; kk < 4; ++kk) {
      bf16x8v af[2];
#pragma unroll
      for (int mt = 0; mt < 2; ++mt)
        af[mt] = *(const bf16x8v*)(sm_p + (w*32+mt*16+l15)*PS + kk*32 + quad*8);
#pragma unroll
      for (int nt = 0; nt < 4; ++nt) {
        bf16x8v bfr = *(const bf16x8v*)(sm_xst + (nt*16+l15)*PS + kk*32 + quad*8);
        oacc[0][nt] = __builtin_amdgcn_mfma_f32_16x16x32_bf16(af[0], bfr, oacc[0][nt], 0, 0, 0);
        oacc[1][nt] = __builtin_amdgcn_mfma_f32_16x16x32_bf16(af[1], bfr, oacc[1][nt], 0, 0, 0);
      }
    }
  }
#pragma unroll
  for (int mt = 0; mt < 2; ++mt)
#pragma unroll
    for (int nt = 0; nt < 4; ++nt)
#pragma unroll
      for (int reg = 0; reg < 4; ++reg) {
        int row = w * 32 + mt * 16 + quad * 4 + reg;
        int col = nt * 16 + l15;
        size_t idx = (size_t)((size_t)b * T_DIM + t0 + row) * C_DIM + col;
        out[idx] = x[idx] + oacc[mt][nt][reg];
      }
}

extern "C" void kernel_launch(void* const* d_in, const int* in_sizes, int n_in,
                              void* d_out, int out_size, void* d_ws, size_t ws_size,
                              hipStream_t stream) {
  const float* x  = (const float*)d_in[0];
  const float* rs = (const float*)d_in[1];
  float* outp = (float*)d_out;
  int B = in_sizes[0] / (T_DIM * C_DIM);
  if (B < 1) B = 1;
  size_t xel = (size_t)B * T_DIM * C_DIM;
  size_t need = xel * 2 * 2 + (size_t)B * T_DIM * 4;
  if (ws_size >= need) {
    unsigned short* xbf  = (unsigned short*)d_ws;
    unsigned short* xtbf = xbf + xel;
    float* sq = (float*)(xtbf + xel);
    pre_cast<<<dim3(T_DIM / 64, B), 256, 0, stream>>>(x, xbf, xtbf, sq);
    gauss_main<<<dim3(T_DIM / BT, B), 512, 0, stream>>>(x, xbf, xtbf, sq, rs, outp);
  } else {
    gauss_attn_f32<<<dim3(T_DIM / BT, B), 256, 0, stream>>>(x, rs, outp);
  }
}